// Round 3
// baseline (267.262 us; speedup 1.0000x reference)
//
#include <hip/hip_runtime.h>
#include <math.h>

constexpr int C  = 128;
constexpr int H  = 128;
constexpr int Wd = 128;
constexpr int HW = H * Wd;
constexpr int LH = 64, LW = 64;
constexpr int PW = 132;                 // k/v row width (x-pad 2 each side)
constexpr int KVPLANE = H * PW;         // 16896 floats, 128 rows
constexpr int KVSZ = 2 * C * KVPLANE;   // 4,325,376 floats per buffer

// 4-byte-aligned float4 for unaligned vector loads of window rows
struct __attribute__((packed, aligned(4))) f4u { float x, y, z, w; };

// ---------------------------------------------------------------------------
// Kernel 1 (pre): per (n,c) 16x16 tile:
//   bilinear upsample lr (align_corners) -> lr_up (d_out) ; q,k,v dwconv3x3.
//   k,v stored x-padded (132-wide, zero cols {0,1,130,131}); q unpadded.
//   Blocks (0,0,nc) zero the x-pad columns of plane nc (ws is poisoned).
// ---------------------------------------------------------------------------
__global__ __launch_bounds__(256) void k_pre(
    const float* __restrict__ hr, const float* __restrict__ lr,
    const float* __restrict__ wq, const float* __restrict__ bq,
    const float* __restrict__ wk, const float* __restrict__ bk,
    const float* __restrict__ wv, const float* __restrict__ bv,
    float* __restrict__ lrup_out, float* __restrict__ qout,
    float* __restrict__ kpad, float* __restrict__ vpad)
{
  __shared__ float tl[18][18];
  __shared__ float th[18][18];
  const int nc = blockIdx.z;
  const float* lsrc = lr + nc * (LH * LW);
  const float* hsrc = hr + nc * HW;
  const float scale = 63.0f / 127.0f;

  for (int h = threadIdx.x; h < 18 * 18; h += 256) {
    const int hy = h / 18, hx = h - hy * 18;
    const int gy = blockIdx.y * 16 + hy - 1;
    const int gx = blockIdx.x * 16 + hx - 1;
    float lv = 0.f, hv = 0.f;
    if (gy >= 0 && gy < H && gx >= 0 && gx < Wd) {
      const float fy = gy * scale, fx = gx * scale;
      const int y0 = (int)fy, x0 = (int)fx;
      const float wy = fy - y0, wx = fx - x0;
      const int y1 = min(y0 + 1, LH - 1), x1 = min(x0 + 1, LW - 1);
      const float* r0 = lsrc + y0 * LW;
      const float* r1 = lsrc + y1 * LW;
      const float a = r0[x0], b = r0[x1], c2 = r1[x0], d = r1[x1];
      const float t0 = a + (b - a) * wx;
      const float t1 = c2 + (d - c2) * wx;
      lv = t0 + (t1 - t0) * wy;
      hv = hsrc[gy * Wd + gx];
    }
    tl[hy][hx] = lv;
    th[hy][hx] = hv;
  }
  __syncthreads();

  const int tx = threadIdx.x & 15, ty = threadIdx.x >> 4;
  const int c = nc & (C - 1);
  const float* wqc = wq + c * 9;
  const float* wkc = wk + c * 9;
  const float* wvc = wv + c * 9;
  float aq = bq[c], ak = bk[c], av = bv[c];
#pragma unroll
  for (int i = 0; i < 3; i++)
#pragma unroll
    for (int j = 0; j < 3; j++) {
      const float tL = tl[ty + i][tx + j];
      const float tH = th[ty + i][tx + j];
      aq += wqc[i * 3 + j] * tL;
      ak += wkc[i * 3 + j] * tH;
      av += wvc[i * 3 + j] * tH;
    }

  const int gy = blockIdx.y * 16 + ty, gx = blockIdx.x * 16 + tx;
  lrup_out[nc * HW + gy * Wd + gx] = tl[ty + 1][tx + 1];
  qout[nc * HW + gy * Wd + gx] = aq;
  const int pidx = nc * KVPLANE + gy * PW + (gx + 2);
  kpad[pidx] = ak;
  vpad[pidx] = av;

  // zero the 4 pad columns of this plane: 128 rows x {0,1,130,131}, k & v
  if (blockIdx.x == 0 && blockIdx.y == 0) {
    for (int i = threadIdx.x; i < 2 * 512; i += 256) {
      float* buf = (i < 512) ? kpad : vpad;
      const int r = i & 511;
      const int y = r >> 2, m = r & 3;
      const int x = m + (m >> 1) * 128;     // {0,1,130,131}
      buf[nc * KVPLANE + y * PW + x] = 0.f;
    }
  }
}

// ---------------------------------------------------------------------------
// Kernel 2 (attn + gating fused).
// Block 256 = 4 waves; wave = 4 px (consecutive x) x 16 channel-groups (8 ch).
// lane = cg*4 + px. Per thread: 8 channels.
//  loop1: sim[25] += q*k (float4 rows from x-padded k), dyn partials
//  wave butterfly (__shfl_xor 4/8/16/32) reduces sim & dyn over cg
//  softmax + sigmoid gates (redundant per lane)
//  loop2: out = lr_up + d0 * sum_k w_k*v + d1 * v_center
// y-boundary rows: wave-uniform predicates (sim stays 0 = zero-pad semantics).
// grid (8,128,2) = 2048 blocks.
// ---------------------------------------------------------------------------
__global__ __launch_bounds__(256) void k_attn2(
    const float* __restrict__ qbuf, const float* __restrict__ kpad,
    const float* __restrict__ vpad, const float* __restrict__ wa,
    const float* __restrict__ ba, float* __restrict__ outb)
{
  __shared__ __align__(16) float wsh[4608];   // wa: (2,256,3,3)
  for (int i = threadIdx.x; i < 1152; i += 256)
    ((float4*)wsh)[i] = ((const float4*)wa)[i];
  __syncthreads();

  const int tid = threadIdx.x;
  const int lane = tid & 63, wv_ = tid >> 6;
  const int px = lane & 3, cg = lane >> 2;
  const int x = blockIdx.x * 16 + wv_ * 4 + px;
  const int y = blockIdx.y;
  const int n = blockIdx.z;
  const int c0 = cg * 8;

  float sim[25];
#pragma unroll
  for (int k = 0; k < 25; k++) sim[k] = 0.f;
  float d0a = 0.f, d1a = 0.f;

  const bool xg1 = (x >= 1), xl126 = (x <= 126);

#pragma unroll 2
  for (int ci = 0; ci < 8; ci++) {
    const int c = c0 + ci;
    const int nc = n * C + c;

    // q 3x3 (unpadded; row predicates uniform, col masks per-lane)
    const float* qb = qbuf + nc * HW + y * Wd + x;
    float q3[9];
#pragma unroll
    for (int dy = 0; dy < 3; dy++) {
      q3[dy * 3 + 0] = 0.f; q3[dy * 3 + 1] = 0.f; q3[dy * 3 + 2] = 0.f;
      if (y + dy >= 1 && y + dy <= H) {          // row y+dy-1 in range
        const f4u a = *(const f4u*)(qb + (dy - 1) * Wd - 1);
        q3[dy * 3 + 0] = xg1 ? a.x : 0.f;
        q3[dy * 3 + 1] = a.y;
        q3[dy * 3 + 2] = xl126 ? a.z : 0.f;
      }
    }
    const float qv = q3[4];  // center

    // k 5x5 window rows (x-padded plane; row predicates uniform)
    const float* kb = kpad + nc * KVPLANE + y * PW + x;   // padded col x-2 tap
    float k3[9];
#pragma unroll
    for (int t = 0; t < 9; t++) k3[t] = 0.f;
#pragma unroll
    for (int r = 0; r < 5; r++) {
      if (y + r >= 2 && y + r < H + 2) {         // row y+r-2 in range
        const f4u a = *(const f4u*)(kb + (r - 2) * PW);
        const float b5 = kb[(r - 2) * PW + 4];
        sim[r * 5 + 0] += qv * a.x;
        sim[r * 5 + 1] += qv * a.y;
        sim[r * 5 + 2] += qv * a.z;
        sim[r * 5 + 3] += qv * a.w;
        sim[r * 5 + 4] += qv * b5;
        if (r >= 1 && r <= 3) {
          k3[(r - 1) * 3 + 0] = a.y;             // dx=-1 (zero ring at edges)
          k3[(r - 1) * 3 + 1] = a.z;             // dx= 0
          k3[(r - 1) * 3 + 2] = a.w;             // dx=+1
        }
      }
    }

    // gating conv partials: channel c (q-half) and C+c (k-half)
    const float* wq0 = &wsh[c * 9];
    const float* wq1 = &wsh[2304 + c * 9];
    const float* wk0 = &wsh[(C + c) * 9];
    const float* wk1 = &wsh[2304 + (C + c) * 9];
#pragma unroll
    for (int t = 0; t < 9; t++) {
      d0a += wq0[t] * q3[t] + wk0[t] * k3[t];
      d1a += wq1[t] * q3[t] + wk1[t] * k3[t];
    }
  }

  // butterfly-reduce over cg (lane bits 2..5); all lanes end with totals
#pragma unroll
  for (int k = 0; k < 25; k++) {
    float s = sim[k];
    s += __shfl_xor(s, 4);
    s += __shfl_xor(s, 8);
    s += __shfl_xor(s, 16);
    s += __shfl_xor(s, 32);
    sim[k] = s;
  }
  {
    float s = d0a;
    s += __shfl_xor(s, 4); s += __shfl_xor(s, 8);
    s += __shfl_xor(s, 16); s += __shfl_xor(s, 32);
    d0a = s;
    s = d1a;
    s += __shfl_xor(s, 4); s += __shfl_xor(s, 8);
    s += __shfl_xor(s, 16); s += __shfl_xor(s, 32);
    d1a = s;
  }
  const float d0 = 1.f / (1.f + expf(-(d0a + ba[0])));
  const float d1 = 1.f / (1.f + expf(-(d1a + ba[1])));

  // softmax over 25 (redundant in all lanes); OOB taps have sim=0 as in ref
  float m = sim[0];
#pragma unroll
  for (int k = 1; k < 25; k++) m = fmaxf(m, sim[k]);
  float tot = 0.f;
#pragma unroll
  for (int k = 0; k < 25; k++) {
    const float e = expf(sim[k] - m);
    sim[k] = e;
    tot += e;
  }
  const float inv = 1.f / tot;
#pragma unroll
  for (int k = 0; k < 25; k++) sim[k] *= inv;

  // value pass + epilogue
#pragma unroll 2
  for (int ci = 0; ci < 8; ci++) {
    const int c = c0 + ci;
    const int nc = n * C + c;
    const float* vb = vpad + nc * KVPLANE + y * PW + x;
    float acc = 0.f, vc = 0.f;
#pragma unroll
    for (int r = 0; r < 5; r++) {
      if (y + r >= 2 && y + r < H + 2) {
        const f4u a = *(const f4u*)(vb + (r - 2) * PW);
        const float b5 = vb[(r - 2) * PW + 4];
        acc += sim[r * 5 + 0] * a.x + sim[r * 5 + 1] * a.y +
               sim[r * 5 + 2] * a.z + sim[r * 5 + 3] * a.w +
               sim[r * 5 + 4] * b5;
        if (r == 2) vc = a.z;  // center tap
      }
    }
    float* op = outb + nc * HW + y * Wd + x;
    *op = *op + d0 * acc + d1 * vc;  // op holds lr_up from k_pre
  }
}

// ---------------------------------------------------------------------------
extern "C" void kernel_launch(void* const* d_in, const int* in_sizes, int n_in,
                              void* d_out, int out_size, void* d_ws,
                              size_t ws_size, hipStream_t stream)
{
  const float* hr = (const float*)d_in[0];
  const float* lr = (const float*)d_in[1];
  const float* wq = (const float*)d_in[2];
  const float* bq = (const float*)d_in[3];
  const float* wk = (const float*)d_in[4];
  const float* bk = (const float*)d_in[5];
  const float* wv = (const float*)d_in[6];
  const float* bv = (const float*)d_in[7];
  const float* wa = (const float*)d_in[8];
  const float* ba = (const float*)d_in[9];

  float* out = (float*)d_out;
  float* ws  = (float*)d_ws;

  // ws footprint: 2*KVSZ + 2*C*HW = 12,845,056 floats = 49.0 MiB
  float* kpad = ws;
  float* vpad = kpad + KVSZ;
  float* qb   = vpad + KVSZ;   // q last: its (x-1) edge reads land in vpad

  k_pre<<<dim3(8, 8, 2 * C), dim3(256), 0, stream>>>(
      hr, lr, wq, bq, wk, bk, wv, bv, out, qb, kpad, vpad);
  k_attn2<<<dim3(8, 128, 2), dim3(256), 0, stream>>>(
      qb, kpad, vpad, wa, ba, out);
}